// Round 3
// baseline (550.088 us; speedup 1.0000x reference)
//
#include <hip/hip_runtime.h>

// Problem: h_t = alpha_t * h_{t-1} + x_t over S, per (batch, channel). B=4, S=8192, D=1024 fp32.
// Single-pass chunked scan with decoupled lookback (rocPRIM/CUB style):
//   - one block per (b, chunk); chunk data held ENTIRELY in registers (no re-read pass)
//   - ticket-based virtual block id => lookback only waits on already-started blocks (deadlock-free)
//   - cross-XCD visibility via agent-scope write-through atomics + release flag
constexpr int B  = 4;
constexpr int S  = 8192;
constexpr int D  = 1024;
constexpr int C  = 512;        // chunks per batch
constexpr int L  = S / C;      // 16 rows per chunk -> 32 float4/thread of register state
constexpr int D4 = D / 4;      // 256 float4 per row = one 256-thread block
constexpr int R  = B * C;      // 2048 records == grid size

typedef float nt_float4 __attribute__((ext_vector_type(4)));

// 8-byte write-through / cache-bypassing accessors (agent scope => coherent across XCDs).
__device__ __forceinline__ void store2(unsigned long long* p, float a, float b) {
    union { float f[2]; unsigned long long u; } v; v.f[0] = a; v.f[1] = b;
    __hip_atomic_store(p, v.u, __ATOMIC_RELAXED, __HIP_MEMORY_SCOPE_AGENT);
}
__device__ __forceinline__ void load2(unsigned long long* p, float& a, float& b) {
    union { float f[2]; unsigned long long u; } v;
    v.u = __hip_atomic_load(p, __ATOMIC_RELAXED, __HIP_MEMORY_SCOPE_AGENT);
    a = v.f[0]; b = v.f[1];
}

__global__ __launch_bounds__(256, 2) void scan_fused(const float4* __restrict__ x,
                                                     const float4* __restrict__ a,
                                                     float4* __restrict__ out,
                                                     unsigned long long* __restrict__ Xagg,
                                                     unsigned long long* __restrict__ Aagg,
                                                     unsigned long long* __restrict__ Carr,
                                                     int* __restrict__ flags,
                                                     int* __restrict__ ticket) {
    const int t = threadIdx.x;
    __shared__ int svid;
    if (t == 0) svid = atomicAdd(ticket, 1);   // device-scope; start order == ticket order
    __syncthreads();
    const int vid = svid;
    const int b = vid & (B - 1);               // chains interleaved round-robin over batches
    const int c = vid >> 2;                    // chunk position within the chain
    const int r = b * C + c;                   // record index

    const long base = ((long)(b * S + c * L)) * D4 + t;

    // ---- Load chunk straight into register state: Xs[s]=x_s, Ps[s]=alpha_s (32 indep dwordx4).
    float4 Xs[L], Ps[L];
    #pragma unroll
    for (int s = 0; s < L; ++s) {
        Xs[s] = x[base + (long)s * D4];
        Ps[s] = a[base + (long)s * D4];
    }
    // ---- In-place zero-carry inclusive scan: Xs[s] = h_s(h_in=0), Ps[s] = prod(alpha_0..s).
    // NOTE: Xs update uses Ps[s] (raw alpha_s) BEFORE Ps[s] is overwritten by the product.
    #pragma unroll
    for (int s = 1; s < L; ++s) {
        Xs[s].x = fmaf(Ps[s].x, Xs[s-1].x, Xs[s].x);
        Xs[s].y = fmaf(Ps[s].y, Xs[s-1].y, Xs[s].y);
        Xs[s].z = fmaf(Ps[s].z, Xs[s-1].z, Xs[s].z);
        Xs[s].w = fmaf(Ps[s].w, Xs[s-1].w, Xs[s].w);
        Ps[s].x *= Ps[s-1].x; Ps[s].y *= Ps[s-1].y;
        Ps[s].z *= Ps[s-1].z; Ps[s].w *= Ps[s-1].w;
    }

    // ---- Publish aggregate (flag=1). c==0 skips: it goes straight to flag=2, so a walker
    // at a chain head can only ever see 0 or 2 (never walks below the chain start).
    if (c > 0) {
        const long o = ((long)r * D4 + t) * 2;
        store2(Xagg + o,     Xs[L-1].x, Xs[L-1].y);
        store2(Xagg + o + 1, Xs[L-1].z, Xs[L-1].w);
        store2(Aagg + o,     Ps[L-1].x, Ps[L-1].y);
        store2(Aagg + o + 1, Ps[L-1].z, Ps[L-1].w);
        __syncthreads();   // drains vmcnt for all waves before the flag store
        if (t == 0) __hip_atomic_store(&flags[r], 1, __ATOMIC_RELEASE, __HIP_MEMORY_SCOPE_AGENT);
    }

    // ---- Decoupled lookback: combine predecessor aggregates until an inclusive carry found.
    float4 carry = {0.f, 0.f, 0.f, 0.f};
    if (c > 0) {
        float4 Ar = {1.f, 1.f, 1.f, 1.f};
        float4 Xr = {0.f, 0.f, 0.f, 0.f};
        for (int k = r - 1;;) {
            int f;
            while ((f = __hip_atomic_load(&flags[k], __ATOMIC_RELAXED,
                                          __HIP_MEMORY_SCOPE_AGENT)) == 0)
                __builtin_amdgcn_s_sleep(1);
            const long o = ((long)k * D4 + t) * 2;   // flag value gates data loads (control dep)
            if (f == 2) {                            // inclusive carry available
                float cx, cy, cz, cw;
                load2(Carr + o, cx, cy); load2(Carr + o + 1, cz, cw);
                carry.x = fmaf(Ar.x, cx, Xr.x);
                carry.y = fmaf(Ar.y, cy, Xr.y);
                carry.z = fmaf(Ar.z, cz, Xr.z);
                carry.w = fmaf(Ar.w, cw, Xr.w);
                break;
            }
            float4 Xk, Ak;                           // aggregate only: keep walking back
            load2(Xagg + o, Xk.x, Xk.y); load2(Xagg + o + 1, Xk.z, Xk.w);
            load2(Aagg + o, Ak.x, Ak.y); load2(Aagg + o + 1, Ak.z, Ak.w);
            Xr.x = fmaf(Ar.x, Xk.x, Xr.x); Xr.y = fmaf(Ar.y, Xk.y, Xr.y);
            Xr.z = fmaf(Ar.z, Xk.z, Xr.z); Xr.w = fmaf(Ar.w, Xk.w, Xr.w);
            Ar.x *= Ak.x; Ar.y *= Ak.y; Ar.z *= Ak.z; Ar.w *= Ak.w;
            --k;
        }
    }

    // ---- Publish inclusive carry (flag=2).
    {
        const long o = ((long)r * D4 + t) * 2;
        float4 co;
        co.x = fmaf(Ps[L-1].x, carry.x, Xs[L-1].x);
        co.y = fmaf(Ps[L-1].y, carry.y, Xs[L-1].y);
        co.z = fmaf(Ps[L-1].z, carry.z, Xs[L-1].z);
        co.w = fmaf(Ps[L-1].w, carry.w, Xs[L-1].w);
        store2(Carr + o, co.x, co.y); store2(Carr + o + 1, co.z, co.w);
    }
    __syncthreads();
    if (t == 0) __hip_atomic_store(&flags[r], 2, __ATOMIC_RELEASE, __HIP_MEMORY_SCOPE_AGENT);

    // ---- Final: h_s = Xs[s] + Ps[s]*carry. Nontemporal stores (out never re-read).
    nt_float4* ntout = (nt_float4*)out;
    #pragma unroll
    for (int s = 0; s < L; ++s) {
        nt_float4 hv = { fmaf(Ps[s].x, carry.x, Xs[s].x),
                         fmaf(Ps[s].y, carry.y, Xs[s].y),
                         fmaf(Ps[s].z, carry.z, Xs[s].z),
                         fmaf(Ps[s].w, carry.w, Xs[s].w) };
        __builtin_nontemporal_store(hv, &ntout[base + (long)s * D4]);
    }
}

extern "C" void kernel_launch(void* const* d_in, const int* in_sizes, int n_in,
                              void* d_out, int out_size, void* d_ws, size_t ws_size,
                              hipStream_t stream) {
    const float4* x = (const float4*)d_in[0];
    const float4* a = (const float4*)d_in[1];
    float4* out = (float4*)d_out;

    // Workspace: [ticket 4B | pad | flags R*4B] (16 KiB, zeroed each launch)
    //            | Xagg 8 MiB | Aagg 8 MiB | Carr 8 MiB  => 24 MiB + 16 KiB total.
    char* ws = (char*)d_ws;
    int* ticket = (int*)ws;
    int* flags  = (int*)(ws + 256);
    unsigned long long* Xagg = (unsigned long long*)(ws + 16384);
    unsigned long long* Aagg = Xagg + (size_t)R * D4 * 2;
    unsigned long long* Carr = Aagg + (size_t)R * D4 * 2;

    hipMemsetAsync(ws, 0, 16384, stream);   // reset ticket + flags (graph-capturable)
    scan_fused<<<dim3(R), 256, 0, stream>>>(x, a, out, Xagg, Aagg, Carr, flags, ticket);
}